// Round 1
// baseline (35.187 us; speedup 1.0000x reference)
//
#include <hip/hip_runtime.h>
#include <stdint.h>

// FSUConv2d single-cycle bipolar forward, reduced to binary XNOR-conv:
//   pc(n,co,h,w) = 576 - S_x(n,h,w) - S_w(co) + 2*sum_{kh,kw} popc(xpack & wpack) + b_bit(co)
//   out = (pc >= 577) ? 1.0f : 0.0f     (clip to +-2048 is a no-op since 0<=pc<=577)
// CIN = 64 exactly matches one uint64 bit-pack across channels.

#define NB   16
#define CIN  64
#define HH   56
#define WWD  56
#define COUT 64
#define HW   (HH * WWD)

// ---- kernel 1: pack x bits across channels into uint64 per (n,h,w) ----
__global__ __launch_bounds__(256) void pack_x_kernel(const float* __restrict__ x,
                                                     uint64_t* __restrict__ xpack) {
    int idx = blockIdx.x * blockDim.x + threadIdx.x;  // n*HW + hw
    if (idx >= NB * HW) return;
    int n  = idx / HW;
    int hw = idx - n * HW;
    const float* xp = x + (size_t)n * CIN * HW + hw;
    uint64_t bits = 0;
#pragma unroll
    for (int c = 0; c < CIN; ++c) {
        bits |= (uint64_t)(xp[(size_t)c * HW] != 0.0f) << c;
    }
    xpack[idx] = bits;
}

// ---- kernel 2: pack w bits across channels into uint64 per (co,kh,kw) ----
__global__ __launch_bounds__(64) void pack_w_kernel(const float* __restrict__ w,
                                                    uint64_t* __restrict__ wpack) {
    int idx = blockIdx.x * blockDim.x + threadIdx.x;  // co*9 + j
    if (idx >= COUT * 9) return;
    int co = idx / 9;
    int j  = idx - co * 9;
    uint64_t bits = 0;
#pragma unroll
    for (int c = 0; c < CIN; ++c) {
        bits |= (uint64_t)(w[(size_t)co * CIN * 9 + c * 9 + j] > 0.0f) << c;
    }
    wpack[idx] = bits;
}

// ---- kernel 3: binary conv + threshold ----
__global__ __launch_bounds__(256) void conv_kernel(const uint64_t* __restrict__ xpack,
                                                   const uint64_t* __restrict__ wpack,
                                                   const float* __restrict__ bias,
                                                   float* __restrict__ out) {
    __shared__ uint64_t wsh[COUT * 9];
    for (int i = threadIdx.x; i < COUT * 9; i += blockDim.x) wsh[i] = wpack[i];
    __syncthreads();

    int idx = blockIdx.x * blockDim.x + threadIdx.x;  // n*COUT*HW + co*HW + hw
    if (idx >= NB * COUT * HW) return;
    int hw = idx % HW;
    int t  = idx / HW;
    int co = t % COUT;
    int n  = t / COUT;
    int h  = hw / WWD;
    int w  = hw - h * WWD;

    const uint64_t* xbase = xpack + (size_t)n * HW;

    int acc = 0;   // accumulates 2*popc(x&w) - popc(x) over valid taps
    int Sw  = 0;   // sum of weight bits over all 9 taps
#pragma unroll
    for (int kh = 0; kh < 3; ++kh) {
        int hh = h + kh - 1;
#pragma unroll
        for (int kw = 0; kw < 3; ++kw) {
            int wc = w + kw - 1;
            uint64_t wp = wsh[co * 9 + kh * 3 + kw];
            Sw += __popcll(wp);
            if (hh >= 0 && hh < HH && wc >= 0 && wc < WWD) {
                uint64_t xv = xbase[hh * WWD + wc];
                acc += 2 * __popcll(xv & wp) - __popcll(xv);
            }
        }
    }
    int bbit = (bias[co] > 0.0f) ? 1 : 0;
    int pc = 576 - Sw + acc + bbit;
    out[idx] = (pc >= 577) ? 1.0f : 0.0f;
}

extern "C" void kernel_launch(void* const* d_in, const int* in_sizes, int n_in,
                              void* d_out, int out_size, void* d_ws, size_t ws_size,
                              hipStream_t stream) {
    const float* x    = (const float*)d_in[0];
    const float* wgt  = (const float*)d_in[1];
    const float* bias = (const float*)d_in[2];
    float* out = (float*)d_out;

    // workspace layout: [0, 4608) wpack ; [8192, 8192+401408) xpack
    uint64_t* wpack = (uint64_t*)d_ws;
    uint64_t* xpack = (uint64_t*)((char*)d_ws + 8192);

    {
        int total = NB * HW;  // 50176
        pack_x_kernel<<<(total + 255) / 256, 256, 0, stream>>>(x, xpack);
    }
    {
        int total = COUT * 9;  // 576
        pack_w_kernel<<<(total + 63) / 64, 64, 0, stream>>>(wgt, wpack);
    }
    {
        int total = NB * COUT * HW;  // 3211264
        conv_kernel<<<(total + 255) / 256, 256, 0, stream>>>(xpack, wpack, bias, out);
    }
}

// Round 2
// 21.571 us; speedup vs baseline: 1.6312x; 1.6312x over previous
//
#include <hip/hip_runtime.h>
#include <stdint.h>

// FSUConv2d single-cycle bipolar forward, reduced to binary XNOR-conv.
// Identity: per tap, popc(x&w) + popc(~x&~w) = 64 - popc(x^w); zero-padding
// (x bit = 0) gives 64 - popc(w) per padded tap, which matches the same
// formula with xv = 0. So with a zero-padded bit-pack P:
//   pc = 576 - S + b_bit,  S = sum_{9 taps} popc(P ^ wp)
//   out = (pc >= 577) = (S == 0 && b_bit)          (clip +-2048 is a no-op)

#define NB   16
#define CIN  64
#define HH   56
#define WWD  56
#define COUT 64
#define HW   (HH * WWD)            // 3136
#define PSTRIDE 64                 // padded row stride (words)
#define PROWS   58                 // 56 + 2 pad rows
#define PWORDS  (PROWS * PSTRIDE)  // 3712 words per image
#define XPACK_WORDS (NB * PWORDS)  // 59392

// ---- kernel 1: zero padded xpack + pack weight bits ----
__global__ __launch_bounds__(256) void prep_kernel(const float* __restrict__ w,
                                                   uint64_t* __restrict__ xpack,
                                                   uint64_t* __restrict__ wpack) {
    int tid = blockIdx.x * 256 + threadIdx.x;
    if (tid < XPACK_WORDS) xpack[tid] = 0ull;
    if (tid < COUT * 9) {
        int co = tid / 9;
        int j  = tid - co * 9;
        uint64_t bits = 0;
#pragma unroll
        for (int c = 0; c < CIN; ++c) {
            bits |= (uint64_t)(w[(size_t)co * CIN * 9 + c * 9 + j] > 0.0f) << c;
        }
        wpack[tid] = bits;
    }
}

// ---- kernel 2: pack x bits into padded layout; 8 channels per thread ----
// thread -> (cg, pos); pos = n*HW + hw, cg selects channels [cg*8, cg*8+8)
// writes one byte (byte cg of the u64 word) -> bit c lands at bit position c.
__global__ __launch_bounds__(256) void pack_x_kernel(const float* __restrict__ x,
                                                     uint8_t* __restrict__ xpack_b) {
    int tid = blockIdx.x * 256 + threadIdx.x;        // [0, 8*NB*HW)
    int pos = tid % (NB * HW);
    int cg  = tid / (NB * HW);
    int n   = pos / HW;
    int hw  = pos - n * HW;
    int h   = hw / WWD;
    int w   = hw - h * WWD;
    const float* xp = x + (size_t)n * CIN * HW + (size_t)(cg * 8) * HW + hw;
    uint32_t b = 0;
#pragma unroll
    for (int i = 0; i < 8; ++i) {
        b |= (uint32_t)(xp[(size_t)i * HW] != 0.0f) << i;
    }
    size_t word = (size_t)n * PWORDS + (size_t)(h + 1) * PSTRIDE + (w + 1);
    xpack_b[word * 8 + cg] = (uint8_t)b;
}

// ---- kernel 3: XNOR conv + threshold; 4 outputs (along w) per thread ----
__global__ __launch_bounds__(256) void conv_kernel(const uint64_t* __restrict__ xpack,
                                                   const uint64_t* __restrict__ wpack,
                                                   const float* __restrict__ bias,
                                                   float* __restrict__ out) {
    __shared__ uint64_t wsh[COUT * 9];
    for (int i = threadIdx.x; i < COUT * 9; i += 256) wsh[i] = wpack[i];
    __syncthreads();

    int tid = blockIdx.x * 256 + threadIdx.x;   // [0, NB*COUT*HW/4) = [0, 802816)
    int q     = tid % 784;                      // hw-group (4 outputs)
    int plane = tid / 784;                      // n*64 + co
    int co = plane & 63;
    int n  = plane >> 6;
    int h  = q / 14;
    int w0 = (q - h * 14) * 4;

    // P[h+kh][w0 + o + kw] for kh in [0,3), o+kw in [0,6)
    const uint64_t* P = xpack + (size_t)n * PWORDS + (size_t)h * PSTRIDE + w0;

    uint64_t r0[6], r1[6], r2[6];
    {
        const ulonglong2* p0 = (const ulonglong2*)(P);
        const ulonglong2* p1 = (const ulonglong2*)(P + PSTRIDE);
        const ulonglong2* p2 = (const ulonglong2*)(P + 2 * PSTRIDE);
        ulonglong2 a, b, c;
        a = p0[0]; b = p0[1]; c = p0[2];
        r0[0]=a.x; r0[1]=a.y; r0[2]=b.x; r0[3]=b.y; r0[4]=c.x; r0[5]=c.y;
        a = p1[0]; b = p1[1]; c = p1[2];
        r1[0]=a.x; r1[1]=a.y; r1[2]=b.x; r1[3]=b.y; r1[4]=c.x; r1[5]=c.y;
        a = p2[0]; b = p2[1]; c = p2[2];
        r2[0]=a.x; r2[1]=a.y; r2[2]=b.x; r2[3]=b.y; r2[4]=c.x; r2[5]=c.y;
    }
    uint64_t wp[9];
#pragma unroll
    for (int t = 0; t < 9; ++t) wp[t] = wsh[co * 9 + t];
    int bb = bias[co] > 0.0f;

    float4 res;
    float* rp = &res.x;
#pragma unroll
    for (int o = 0; o < 4; ++o) {
        int S = 0;
#pragma unroll
        for (int kw = 0; kw < 3; ++kw) {
            S += __popcll(r0[o + kw] ^ wp[0 * 3 + kw]);
            S += __popcll(r1[o + kw] ^ wp[1 * 3 + kw]);
            S += __popcll(r2[o + kw] ^ wp[2 * 3 + kw]);
        }
        rp[o] = (S == 0 && bb) ? 1.0f : 0.0f;
    }
    ((float4*)out)[tid] = res;   // out offset = plane*3136 + q*4 = tid*4
}

extern "C" void kernel_launch(void* const* d_in, const int* in_sizes, int n_in,
                              void* d_out, int out_size, void* d_ws, size_t ws_size,
                              hipStream_t stream) {
    const float* x    = (const float*)d_in[0];
    const float* wgt  = (const float*)d_in[1];
    const float* bias = (const float*)d_in[2];
    float* out = (float*)d_out;

    // workspace: [0, 4608) wpack ; [8192, 8192 + 475136) xpack (padded)
    uint64_t* wpack = (uint64_t*)d_ws;
    uint64_t* xpack = (uint64_t*)((char*)d_ws + 8192);

    {
        int total = XPACK_WORDS;                 // 59392 (covers COUT*9 too)
        prep_kernel<<<(total + 255) / 256, 256, 0, stream>>>(wgt, xpack, wpack);
    }
    {
        int total = 8 * NB * HW;                 // 401408
        pack_x_kernel<<<(total + 255) / 256, 256, 0, stream>>>(x, (uint8_t*)xpack);
    }
    {
        int total = NB * COUT * HW / 4;          // 802816
        conv_kernel<<<(total + 255) / 256, 256, 0, stream>>>(xpack, wpack, bias, out);
    }
}

// Round 3
// 17.413 us; speedup vs baseline: 2.0208x; 1.2388x over previous
//
#include <hip/hip_runtime.h>
#include <stdint.h>

// FSUConv2d single-cycle bipolar forward == binary XNOR-conv with threshold:
//   per tap popc(x&w) + popc(~x&~w) = 64 - popc(x^w); zero-padded xpack makes
//   pad taps follow the same formula. pc = 576 - S + b_bit, S = sum popc(x^w).
//   out = (pc >= 577) = (S == 0 && b_bit) = (all 9 tap words EQUAL && b_bit).
// The equality form needs only v_cmp_eq_u64 + s_and_b64 per tap (no popcount).

#define NB   16
#define CIN  64
#define HH   56
#define WWD  56
#define COUT 64
#define HW   (HH * WWD)            // 3136
#define PSTRIDE 64                 // padded row stride (words)
#define PROWS   58
#define PWORDS  (PROWS * PSTRIDE)  // 3712 words per image
#define NPACK (8 * NB * HW)        // 401408 pack threads (8 ch per thread)
#define NPAD  (NB * 228)           // 3648 pad-word zeroing threads
#define NWPK  (COUT * 9)           // 576 weight-pack threads
#define K1TOT (NPACK + NPAD + NWPK)

// ---- kernel 1: pack x bits (byte per 8 channels), zero ONLY the pad words
//      (disjoint addresses -> no race), pack weight bits ----
__global__ __launch_bounds__(256) void prep_pack_kernel(const float* __restrict__ x,
                                                        const float* __restrict__ w,
                                                        uint64_t* __restrict__ xpack,
                                                        uint64_t* __restrict__ wpack) {
    int tid = blockIdx.x * 256 + threadIdx.x;
    if (tid < NPACK) {
        int pos = tid % (NB * HW);
        int cg  = tid / (NB * HW);
        int n   = pos / HW;
        int hw  = pos - n * HW;
        int h   = hw / WWD;
        int ww  = hw - h * WWD;
        const float* xp = x + (size_t)n * CIN * HW + (size_t)(cg * 8) * HW + hw;
        uint32_t b = 0;
#pragma unroll
        for (int i = 0; i < 8; ++i) b |= (uint32_t)(xp[(size_t)i * HW] != 0.0f) << i;
        size_t word = (size_t)n * PWORDS + (size_t)(h + 1) * PSTRIDE + (ww + 1);
        ((uint8_t*)xpack)[word * 8 + cg] = (uint8_t)b;
    } else if (tid < NPACK + NPAD) {
        // pad words actually read by conv: row 0 cols 0..57, row 57 cols 0..57,
        // rows 1..56 cols {0, 57}.  228 words per image.
        int idx = tid - NPACK;
        int n = idx / 228;
        int r = idx - n * 228;
        int row, col;
        if (r < 58)       { row = 0;  col = r; }
        else if (r < 116) { row = 57; col = r - 58; }
        else { int rr = r - 116; row = 1 + (rr >> 1); col = (rr & 1) ? 57 : 0; }
        xpack[(size_t)n * PWORDS + row * PSTRIDE + col] = 0ull;
    } else if (tid < K1TOT) {
        int idx = tid - (NPACK + NPAD);
        int co = idx / 9, j = idx - co * 9;
        uint64_t bits = 0;
#pragma unroll
        for (int c = 0; c < CIN; ++c)
            bits |= (uint64_t)(w[(size_t)co * CIN * 9 + c * 9 + j] > 0.0f) << c;
        wpack[idx] = bits;
    }
}

// ---- kernel 2: equality-conv + threshold; 2 rows x 4 cols per thread ----
__global__ __launch_bounds__(256) void conv_kernel(const uint64_t* __restrict__ xpack,
                                                   const uint64_t* __restrict__ wpack,
                                                   const float* __restrict__ bias,
                                                   float* __restrict__ out) {
    __shared__ uint64_t wsh[COUT * 9];
    for (int i = threadIdx.x; i < COUT * 9; i += 256) wsh[i] = wpack[i];
    __syncthreads();

    int tid = blockIdx.x * 256 + threadIdx.x;   // [0, NB*COUT*HW/8) = [0, 401408)
    int q     = tid % 392;                      // hp*14 + wg
    int plane = tid / 392;                      // n*64 + co
    int co = plane & 63;
    int n  = plane >> 6;
    int hp = q / 14;
    int wg = q - hp * 14;
    int h0 = hp * 2, w0 = wg * 4;

    const uint64_t* P = xpack + (size_t)n * PWORDS + (size_t)h0 * PSTRIDE + w0;
    uint64_t r[4][6];
#pragma unroll
    for (int rr = 0; rr < 4; ++rr) {
        const ulonglong2* p = (const ulonglong2*)(P + rr * PSTRIDE);
        ulonglong2 a = p[0], b = p[1], c = p[2];
        r[rr][0] = a.x; r[rr][1] = a.y; r[rr][2] = b.x;
        r[rr][3] = b.y; r[rr][4] = c.x; r[rr][5] = c.y;
    }
    uint64_t wp[9];
#pragma unroll
    for (int t = 0; t < 9; ++t) wp[t] = wsh[co * 9 + t];
    int bb = bias[co] > 0.0f;

    float res[8];
#pragma unroll
    for (int orow = 0; orow < 2; ++orow) {
#pragma unroll
        for (int o = 0; o < 4; ++o) {
            int e = bb;
#pragma unroll
            for (int kh = 0; kh < 3; ++kh)
#pragma unroll
                for (int kw = 0; kw < 3; ++kw)
                    e &= (r[orow + kh][o + kw] == wp[kh * 3 + kw]);
            res[orow * 4 + o] = e ? 1.0f : 0.0f;
        }
    }
    float* ob = out + (size_t)plane * HW + (size_t)h0 * WWD + w0;
    *(float4*)ob         = *(const float4*)&res[0];
    *(float4*)(ob + WWD) = *(const float4*)&res[4];
}

extern "C" void kernel_launch(void* const* d_in, const int* in_sizes, int n_in,
                              void* d_out, int out_size, void* d_ws, size_t ws_size,
                              hipStream_t stream) {
    const float* x    = (const float*)d_in[0];
    const float* wgt  = (const float*)d_in[1];
    const float* bias = (const float*)d_in[2];
    float* out = (float*)d_out;

    // workspace: [0, 4608) wpack ; [8192, 8192 + 475136) xpack (padded, 16B-aligned)
    uint64_t* wpack = (uint64_t*)d_ws;
    uint64_t* xpack = (uint64_t*)((char*)d_ws + 8192);

    prep_pack_kernel<<<(K1TOT + 255) / 256, 256, 0, stream>>>(x, wgt, xpack, wpack);

    {
        int total = NB * COUT * HW / 8;          // 401408
        conv_kernel<<<(total + 255) / 256, 256, 0, stream>>>(xpack, wpack, bias, out);
    }
}